// Round 11
// baseline (245.479 us; speedup 1.0000x reference)
//
#include <hip/hip_runtime.h>

// LightGCN via running sums: S1 = E + A·E, S2 = E + A·S1, out = 0.25(E + A·S2)
// bf16 storage, f32 accumulate. CSR-by-dst via capacity-padded partition.
// Edge record packed to 4 B: src(19b) | wq(13b fixed-point, /8191).
// offs packed to 4 B: local_beg(16b) | deg(16b). XCD-swizzled node kernels.

#define USER_NUM  300000
#define ITEM_NUM  200000
#define N_NODES   500000
#define EMBED_DIM 64
#define NV   (N_NODES * EMBED_DIM)
#define NV4  (NV / 4)
#define N_EDGES   1250000

#define BSHIFT  11
#define BNODES  2048                               // nodes per coarse bucket
#define NBUK    ((N_NODES + BNODES - 1) / BNODES)  // 245
#define CAP     8192                               // padded slots per bucket
#define PCHUNK  4096                               // edges per partition block
#define PGRID   ((N_EDGES + PCHUNK - 1) / PCHUNK)  // 306
#define CONVG   ((N_NODES * 8) / 256)              // 15625 conv blocks

typedef float f32x4 __attribute__((ext_vector_type(4)));
typedef unsigned long long u64;

// ---------------- bf16 helpers (storage only; math in f32) ----------------
__device__ __forceinline__ unsigned bpack(float lo, float hi) {
    unsigned a = __float_as_uint(lo), b = __float_as_uint(hi);
    a = (a + 0x7fffu + ((a >> 16) & 1u)) >> 16;          // RN-to-even
    b = (b + 0x7fffu + ((b >> 16) & 1u)) & 0xffff0000u;
    return a | b;
}
__device__ __forceinline__ float blo(unsigned u) { return __uint_as_float(u << 16); }
__device__ __forceinline__ float bhi(unsigned u) { return __uint_as_float(u & 0xffff0000u); }

__device__ __forceinline__ void bf8_fma(uint4 g, float w, float* a) {
    a[0] += w * blo(g.x); a[1] += w * bhi(g.x);
    a[2] += w * blo(g.y); a[3] += w * bhi(g.y);
    a[4] += w * blo(g.z); a[5] += w * bhi(g.z);
    a[6] += w * blo(g.w); a[7] += w * bhi(g.w);
}

// decode packed edge: src = v & 0x7FFFF, w = (v>>19) / 8191
__device__ __forceinline__ float wdec(unsigned v) {
    return (float)(v >> 19) * (1.0f / 8191.0f);
}

// bijective XCD swizzle (m204): contiguous node chunk per XCD
__device__ __forceinline__ int swz_block(int bid, int nwg) {
    int q = nwg >> 3, r = nwg & 7;
    int x = bid & 7, i = bid >> 3;
    return (x < r ? x * (q + 1) : r * (q + 1) + (x - r) * q) + i;
}

// -------- fused pre-pass: blocks [0,PGRID) partition edges into padded
// buckets (tmp entry: u64 = wq<<32 | key); blocks [PGRID,..) conv f32->bf16 --
__global__ void pre_kernel(const int* __restrict__ src,
                           const int* __restrict__ dst,
                           const float* __restrict__ w,
                           int* __restrict__ bcur,
                           u64* __restrict__ tmp,
                           const float4* __restrict__ ue,
                           const float4* __restrict__ ie,
                           uint4* __restrict__ E) {
    __shared__ int hist[256];
    __shared__ int rbase[256];
    int t = threadIdx.x;
    if (blockIdx.x >= PGRID) {
        int i = (blockIdx.x - PGRID) * 256 + t;          // [0, N_NODES*8)
        int n = i >> 3, sub = i & 7;
        const f32x4* p = (const f32x4*)((n < USER_NUM) ? &ue[(size_t)n * 16]
                                                       : &ie[(size_t)(n - USER_NUM) * 16]);
        f32x4 a = __builtin_nontemporal_load(&p[sub * 2]);
        f32x4 b = __builtin_nontemporal_load(&p[sub * 2 + 1]);
        uint4 r;
        r.x = bpack(a.x, a.y); r.y = bpack(a.z, a.w);
        r.z = bpack(b.x, b.y); r.w = bpack(b.z, b.w);
        E[i] = r;
        return;
    }
    int cbase = blockIdx.x * PCHUNK;
    int cnt = min(PCHUNK, N_EDGES - cbase);
    unsigned key[16];
    int eb[16], wq[16];
    hist[t] = 0;
    __syncthreads();
    #pragma unroll
    for (int k = 0; k < 16; ++k) {
        int i = t + k * 256;
        if (i < cnt) {
            int e = cbase + i;
            int d = dst[e];
            eb[k]  = d >> BSHIFT;
            key[k] = ((unsigned)(d & (BNODES - 1)) << 19) | (unsigned)src[e];
            wq[k]  = (int)(w[e] * 8191.0f + 0.5f);          // 13-bit fixed
            atomicAdd(&hist[eb[k]], 1);
        } else eb[k] = -1;
    }
    __syncthreads();
    int h = hist[t];
    rbase[t] = (h > 0) ? atomicAdd(&bcur[t], h) : 0;
    __syncthreads();
    hist[t] = 0;                     // reuse as local cursor
    __syncthreads();
    #pragma unroll
    for (int k = 0; k < 16; ++k) {
        if (eb[k] >= 0) {
            int r = atomicAdd(&hist[eb[k]], 1);
            u64 v = ((u64)(unsigned)wq[k] << 32) | (u64)key[k];
            __builtin_nontemporal_store(v, &tmp[(size_t)eb[k] * CAP + rbase[eb[k]] + r]);
        }
    }
}

// -------- per-bucket fine sort: LDS counts+scan -> offs1 packed, pe(4B) --
__global__ void fine_kernel(const u64* __restrict__ tmp,
                            const int* __restrict__ bcur,
                            unsigned* __restrict__ offs1,
                            unsigned* __restrict__ pe) {
    __shared__ int cnt[BNODES];
    __shared__ int sums[256];
    int b = blockIdx.x, t = threadIdx.x;
    int nbase = b << BSHIFT;
    int ebase = b * CAP;
    int ecnt  = bcur[b];
    for (int j = t; j < BNODES; j += 256) cnt[j] = 0;
    __syncthreads();
    for (int i = t; i < ecnt; i += 256) {
        unsigned key = (unsigned)__builtin_nontemporal_load(&tmp[ebase + i]);
        atomicAdd(&cnt[key >> 19], 1);
    }
    __syncthreads();
    int s[8], tot = 0;
    #pragma unroll
    for (int k = 0; k < 8; ++k) { s[k] = cnt[t * 8 + k]; tot += s[k]; }
    sums[t] = tot;
    __syncthreads();
    for (int off = 1; off < 256; off <<= 1) {
        int x = (t >= off) ? sums[t - off] : 0;
        __syncthreads();
        if (t >= off) sums[t] += x;
        __syncthreads();
    }
    int run = sums[t] - tot;                 // bucket-local
    #pragma unroll
    for (int k = 0; k < 8; ++k) {
        int node = nbase + t * 8 + k;
        if (node < N_NODES) offs1[node] = (unsigned)run | ((unsigned)s[k] << 16);
        cnt[t * 8 + k] = ebase + run;        // global cursor
        run += s[k];
    }
    __syncthreads();
    for (int i = t; i < ecnt; i += 256) {
        u64 T = tmp[ebase + i];
        unsigned key = (unsigned)T;
        unsigned wq  = (unsigned)(T >> 32);
        int p = atomicAdd(&cnt[key >> 19], 1);
        pe[p] = (wq << 19) | (key & 0x7FFFFu);
    }
}

// ---- running-sum layer: hout[n] = bf16( E[n] + sum w * hsrc[src] ) ------
__global__ void slayer_kernel(const uint4* __restrict__ hsrc,
                              const uint4* __restrict__ E,
                              uint4* __restrict__ hout,
                              const unsigned* __restrict__ offs1,
                              const unsigned* __restrict__ pe) {
    int blk  = swz_block(blockIdx.x, gridDim.x);
    int gid  = blk * 256 + threadIdx.x;
    int wave = gid >> 6;
    int lane = gid & 63;
    int grp  = lane >> 3;
    int sub  = lane & 7;
    int n    = wave * 8 + grp;
    if (n >= N_NODES) return;
    unsigned ov = offs1[n];
    int beg = (n >> BSHIFT) * CAP + (int)(ov & 0xFFFFu);
    int end = beg + (int)(ov >> 16);
    float a0[8] = {0,0,0,0,0,0,0,0};
    float a1[8] = {0,0,0,0,0,0,0,0};
    int e = beg;
    for (; e + 2 <= end; e += 2) {
        unsigned p0 = pe[e], p1 = pe[e + 1];
        uint4 g0 = hsrc[(size_t)(p0 & 0x7FFFFu) * 8 + sub];
        uint4 g1 = hsrc[(size_t)(p1 & 0x7FFFFu) * 8 + sub];
        bf8_fma(g0, wdec(p0), a0);
        bf8_fma(g1, wdec(p1), a1);
    }
    if (e < end) {
        unsigned p0 = pe[e];
        uint4 g0 = hsrc[(size_t)(p0 & 0x7FFFFu) * 8 + sub];
        bf8_fma(g0, wdec(p0), a0);
    }
    size_t o8 = (size_t)n * 8 + sub;
    uint4 e0 = E[o8];
    a0[0] += a1[0] + blo(e0.x); a0[1] += a1[1] + bhi(e0.x);
    a0[2] += a1[2] + blo(e0.y); a0[3] += a1[3] + bhi(e0.y);
    a0[4] += a1[4] + blo(e0.z); a0[5] += a1[5] + bhi(e0.z);
    a0[6] += a1[6] + blo(e0.w); a0[7] += a1[7] + bhi(e0.w);
    uint4 r;
    r.x = bpack(a0[0], a0[1]); r.y = bpack(a0[2], a0[3]);
    r.z = bpack(a0[4], a0[5]); r.w = bpack(a0[6], a0[7]);
    hout[o8] = r;
}

// final: out = 0.25 * ( E[n] + sum w * S2[src] ), f32 nontemporal out
__global__ void final_kernel(const uint4* __restrict__ E,
                             const uint4* __restrict__ S2,
                             float* __restrict__ out,
                             const unsigned* __restrict__ offs1,
                             const unsigned* __restrict__ pe) {
    int blk  = swz_block(blockIdx.x, gridDim.x);
    int gid  = blk * 256 + threadIdx.x;
    int wave = gid >> 6;
    int lane = gid & 63;
    int grp  = lane >> 3;
    int sub  = lane & 7;
    int n    = wave * 8 + grp;
    if (n >= N_NODES) return;
    unsigned ov = offs1[n];
    int beg = (n >> BSHIFT) * CAP + (int)(ov & 0xFFFFu);
    int end = beg + (int)(ov >> 16);
    float a0[8] = {0,0,0,0,0,0,0,0};
    float a1[8] = {0,0,0,0,0,0,0,0};
    int e = beg;
    for (; e + 2 <= end; e += 2) {
        unsigned p0 = pe[e], p1 = pe[e + 1];
        uint4 g0 = S2[(size_t)(p0 & 0x7FFFFu) * 8 + sub];
        uint4 g1 = S2[(size_t)(p1 & 0x7FFFFu) * 8 + sub];
        bf8_fma(g0, wdec(p0), a0);
        bf8_fma(g1, wdec(p1), a1);
    }
    if (e < end) {
        unsigned p0 = pe[e];
        uint4 g0 = S2[(size_t)(p0 & 0x7FFFFu) * 8 + sub];
        bf8_fma(g0, wdec(p0), a0);
    }
    size_t o8 = (size_t)n * 8 + sub;
    uint4 e0 = E[o8];
    f32x4 ra, rb;
    ra.x = 0.25f * (blo(e0.x) + a0[0] + a1[0]);
    ra.y = 0.25f * (bhi(e0.x) + a0[1] + a1[1]);
    ra.z = 0.25f * (blo(e0.y) + a0[2] + a1[2]);
    ra.w = 0.25f * (bhi(e0.y) + a0[3] + a1[3]);
    rb.x = 0.25f * (blo(e0.z) + a0[4] + a1[4]);
    rb.y = 0.25f * (bhi(e0.z) + a0[5] + a1[5]);
    rb.z = 0.25f * (blo(e0.w) + a0[6] + a1[6]);
    rb.w = 0.25f * (bhi(e0.w) + a0[7] + a1[7]);
    f32x4* op = (f32x4*)out + (size_t)n * 16 + sub * 2;
    __builtin_nontemporal_store(ra, op);
    __builtin_nontemporal_store(rb, op + 1);
}

// ---------------- fallback (round-1 atomic) path ----------------
__global__ void init_fb_kernel(const float4* __restrict__ ue,
                               const float4* __restrict__ ie,
                               float4* __restrict__ h,
                               float4* __restrict__ hn,
                               float4* __restrict__ acc) {
    int i = blockIdx.x * blockDim.x + threadIdx.x;
    if (i >= NV4) return;
    const int ub = USER_NUM * EMBED_DIM / 4;
    float4 v = (i < ub) ? ue[i] : ie[i - ub];
    h[i] = v; acc[i] = v;
    hn[i] = make_float4(0.f, 0.f, 0.f, 0.f);
}

__global__ void spmm_fb_kernel(const float* __restrict__ h, float* __restrict__ hn,
                               const int* __restrict__ src, const int* __restrict__ dst,
                               const float* __restrict__ w) {
    int gid = blockIdx.x * blockDim.x + threadIdx.x;
    int wave = gid >> 6, lane = gid & 63;
    int nwave = (gridDim.x * blockDim.x) >> 6;
    for (int e = wave; e < N_EDGES; e += nwave) {
        float v = h[src[e] * 64 + lane] * w[e];
        atomicAdd(&hn[dst[e] * 64 + lane], v);
    }
}

template <int LAST>
__global__ void accum_fb_kernel(float4* __restrict__ acc, const float4* __restrict__ hn,
                                float4* __restrict__ zbuf) {
    int i = blockIdx.x * blockDim.x + threadIdx.x;
    if (i >= NV4) return;
    float4 a = acc[i], n = hn[i];
    a.x += n.x; a.y += n.y; a.z += n.z; a.w += n.w;
    if (LAST) { a.x *= 0.25f; a.y *= 0.25f; a.z *= 0.25f; a.w *= 0.25f; }
    acc[i] = a;
    if (!LAST) zbuf[i] = make_float4(0.f, 0.f, 0.f, 0.f);
}

extern "C" void kernel_launch(void* const* d_in, const int* in_sizes, int n_in,
                              void* d_out, int out_size, void* d_ws, size_t ws_size,
                              hipStream_t stream) {
    const float* ue  = (const float*)d_in[0];
    const float* ie  = (const float*)d_in[1];
    const float* w   = (const float*)d_in[2];
    const int*   src = (const int*)d_in[3];
    const int*   dst = (const int*)d_in[4];

    float* out = (float*)d_out;

    // workspace: E(64MB), S1(64MB), S2(64MB), tmp(u64 16MB padded),
    //            pe(uint 8MB padded), offs1(2MB), bcur(245)
    const size_t HB   = (size_t)N_NODES * 128;
    const size_t PADE = (size_t)NBUK * CAP;
    char*     base  = (char*)d_ws;
    uint4*    E     = (uint4*)base;
    uint4*    S1    = (uint4*)(base + HB);
    uint4*    S2    = (uint4*)(base + 2 * HB);
    u64*      tmp   = (u64*)(base + 3 * HB);
    unsigned* pe    = (unsigned*)(base + 3 * HB + PADE * 8);
    unsigned* offs1 = (unsigned*)(base + 3 * HB + PADE * 8 + PADE * 4);
    int*      bcur  = (int*)(base + 3 * HB + PADE * 12 + (size_t)N_NODES * 4);

    const size_t needed = 3 * HB + PADE * 12 + (size_t)N_NODES * 4
                        + (size_t)NBUK * 4;

    const int TB = 256;
    const int egrid = NV4 / TB;
    const int fgrid = (N_NODES / 8 * 64) / TB;        // 15625 (8 nodes/wave)

    if (ws_size >= needed) {
        (void)hipMemsetAsync(bcur, 0, (size_t)NBUK * 4, stream);
        pre_kernel<<<PGRID + CONVG, TB, 0, stream>>>(src, dst, w, bcur, tmp,
                                                     (const float4*)ue,
                                                     (const float4*)ie, E);
        fine_kernel<<<NBUK, TB, 0, stream>>>(tmp, bcur, offs1, pe);

        slayer_kernel<<<fgrid, TB, 0, stream>>>(E,  E, S1, offs1, pe);  // S1=E+A·E
        slayer_kernel<<<fgrid, TB, 0, stream>>>(S1, E, S2, offs1, pe);  // S2=E+A·S1
        final_kernel<<<fgrid, TB, 0, stream>>>(E, S2, out, offs1, pe);  // 0.25(E+A·S2)
    } else {
        // ---- fallback: atomic path ----
        float* A  = (float*)d_ws;
        float* Bf = A + NV;
        const int sgrid = 4096;
        init_fb_kernel<<<egrid, TB, 0, stream>>>((const float4*)ue, (const float4*)ie,
                                                 (float4*)A, (float4*)Bf, (float4*)out);
        spmm_fb_kernel<<<sgrid, TB, 0, stream>>>(A, Bf, src, dst, w);
        accum_fb_kernel<0><<<egrid, TB, 0, stream>>>((float4*)out, (const float4*)Bf, (float4*)A);
        spmm_fb_kernel<<<sgrid, TB, 0, stream>>>(Bf, A, src, dst, w);
        accum_fb_kernel<0><<<egrid, TB, 0, stream>>>((float4*)out, (const float4*)A, (float4*)Bf);
        spmm_fb_kernel<<<sgrid, TB, 0, stream>>>(A, Bf, src, dst, w);
        accum_fb_kernel<1><<<egrid, TB, 0, stream>>>((float4*)out, (const float4*)Bf, nullptr);
    }
}

// Round 12
// 208.006 us; speedup vs baseline: 1.1802x; 1.1802x over previous
//
#include <hip/hip_runtime.h>

// LightGCN via running sums: S1 = E + A·E, S2 = E + A·S1, out = 0.25(E + A·S2)
// bf16 storage, f32 accumulate. CSR-by-dst via capacity-padded partition.
// Edge record packed to 4 B: src(19b) | wq(13b fixed-point, /8191).
// offs packed to 4 B: local_beg(16b) | deg(16b). XCD-swizzled node kernels.
// NOTE: nontemporal ONLY on read-once emb loads + write-once out stores.
// (r11 lesson: nt on scattered tmp stores defeats L2 write-combining, 5x amp.)

#define USER_NUM  300000
#define ITEM_NUM  200000
#define N_NODES   500000
#define EMBED_DIM 64
#define NV   (N_NODES * EMBED_DIM)
#define NV4  (NV / 4)
#define N_EDGES   1250000

#define BSHIFT  11
#define BNODES  2048                               // nodes per coarse bucket
#define NBUK    ((N_NODES + BNODES - 1) / BNODES)  // 245
#define CAP     8192                               // padded slots per bucket
#define PCHUNK  4096                               // edges per partition block
#define PGRID   ((N_EDGES + PCHUNK - 1) / PCHUNK)  // 306
#define CONVG   ((N_NODES * 8) / 256)              // 15625 conv blocks

typedef float f32x4 __attribute__((ext_vector_type(4)));
typedef unsigned long long u64;

// ---------------- bf16 helpers (storage only; math in f32) ----------------
__device__ __forceinline__ unsigned bpack(float lo, float hi) {
    unsigned a = __float_as_uint(lo), b = __float_as_uint(hi);
    a = (a + 0x7fffu + ((a >> 16) & 1u)) >> 16;          // RN-to-even
    b = (b + 0x7fffu + ((b >> 16) & 1u)) & 0xffff0000u;
    return a | b;
}
__device__ __forceinline__ float blo(unsigned u) { return __uint_as_float(u << 16); }
__device__ __forceinline__ float bhi(unsigned u) { return __uint_as_float(u & 0xffff0000u); }

__device__ __forceinline__ void bf8_fma(uint4 g, float w, float* a) {
    a[0] += w * blo(g.x); a[1] += w * bhi(g.x);
    a[2] += w * blo(g.y); a[3] += w * bhi(g.y);
    a[4] += w * blo(g.z); a[5] += w * bhi(g.z);
    a[6] += w * blo(g.w); a[7] += w * bhi(g.w);
}

// decode packed edge: src = v & 0x7FFFF, w = (v>>19) / 8191
__device__ __forceinline__ float wdec(unsigned v) {
    return (float)(v >> 19) * (1.0f / 8191.0f);
}

// bijective XCD swizzle (m204): contiguous node chunk per XCD
__device__ __forceinline__ int swz_block(int bid, int nwg) {
    int q = nwg >> 3, r = nwg & 7;
    int x = bid & 7, i = bid >> 3;
    return (x < r ? x * (q + 1) : r * (q + 1) + (x - r) * q) + i;
}

// -------- fused pre-pass: blocks [0,PGRID) partition edges into padded
// buckets (tmp entry: u64 = wq<<32 | key); blocks [PGRID,..) conv f32->bf16 --
__global__ void pre_kernel(const int* __restrict__ src,
                           const int* __restrict__ dst,
                           const float* __restrict__ w,
                           int* __restrict__ bcur,
                           u64* __restrict__ tmp,
                           const float4* __restrict__ ue,
                           const float4* __restrict__ ie,
                           uint4* __restrict__ E) {
    __shared__ int hist[256];
    __shared__ int rbase[256];
    int t = threadIdx.x;
    if (blockIdx.x >= PGRID) {
        int i = (blockIdx.x - PGRID) * 256 + t;          // [0, N_NODES*8)
        int n = i >> 3, sub = i & 7;
        const f32x4* p = (const f32x4*)((n < USER_NUM) ? &ue[(size_t)n * 16]
                                                       : &ie[(size_t)(n - USER_NUM) * 16]);
        f32x4 a = __builtin_nontemporal_load(&p[sub * 2]);
        f32x4 b = __builtin_nontemporal_load(&p[sub * 2 + 1]);
        uint4 r;
        r.x = bpack(a.x, a.y); r.y = bpack(a.z, a.w);
        r.z = bpack(b.x, b.y); r.w = bpack(b.z, b.w);
        E[i] = r;
        return;
    }
    int cbase = blockIdx.x * PCHUNK;
    int cnt = min(PCHUNK, N_EDGES - cbase);
    unsigned key[16];
    int eb[16], wq[16];
    hist[t] = 0;
    __syncthreads();
    #pragma unroll
    for (int k = 0; k < 16; ++k) {
        int i = t + k * 256;
        if (i < cnt) {
            int e = cbase + i;
            int d = dst[e];
            eb[k]  = d >> BSHIFT;
            key[k] = ((unsigned)(d & (BNODES - 1)) << 19) | (unsigned)src[e];
            wq[k]  = (int)(w[e] * 8191.0f + 0.5f);          // 13-bit fixed
            atomicAdd(&hist[eb[k]], 1);
        } else eb[k] = -1;
    }
    __syncthreads();
    int h = hist[t];
    rbase[t] = (h > 0) ? atomicAdd(&bcur[t], h) : 0;
    __syncthreads();
    hist[t] = 0;                     // reuse as local cursor
    __syncthreads();
    #pragma unroll
    for (int k = 0; k < 16; ++k) {
        if (eb[k] >= 0) {
            int r = atomicAdd(&hist[eb[k]], 1);
            // plain store: rely on L2 write-combining of bucket-local runs
            tmp[(size_t)eb[k] * CAP + rbase[eb[k]] + r] =
                ((u64)(unsigned)wq[k] << 32) | (u64)key[k];
        }
    }
}

// -------- per-bucket fine sort: LDS counts+scan -> offs1 packed, pe(4B) --
__global__ void fine_kernel(const u64* __restrict__ tmp,
                            const int* __restrict__ bcur,
                            unsigned* __restrict__ offs1,
                            unsigned* __restrict__ pe) {
    __shared__ int cnt[BNODES];
    __shared__ int sums[256];
    int b = blockIdx.x, t = threadIdx.x;
    int nbase = b << BSHIFT;
    int ebase = b * CAP;
    int ecnt  = bcur[b];
    for (int j = t; j < BNODES; j += 256) cnt[j] = 0;
    __syncthreads();
    for (int i = t; i < ecnt; i += 256) {
        unsigned key = (unsigned)tmp[ebase + i];   // plain load (read again below)
        atomicAdd(&cnt[key >> 19], 1);
    }
    __syncthreads();
    int s[8], tot = 0;
    #pragma unroll
    for (int k = 0; k < 8; ++k) { s[k] = cnt[t * 8 + k]; tot += s[k]; }
    sums[t] = tot;
    __syncthreads();
    for (int off = 1; off < 256; off <<= 1) {
        int x = (t >= off) ? sums[t - off] : 0;
        __syncthreads();
        if (t >= off) sums[t] += x;
        __syncthreads();
    }
    int run = sums[t] - tot;                 // bucket-local
    #pragma unroll
    for (int k = 0; k < 8; ++k) {
        int node = nbase + t * 8 + k;
        if (node < N_NODES) offs1[node] = (unsigned)run | ((unsigned)s[k] << 16);
        cnt[t * 8 + k] = ebase + run;        // global cursor
        run += s[k];
    }
    __syncthreads();
    for (int i = t; i < ecnt; i += 256) {
        u64 T = tmp[ebase + i];
        unsigned key = (unsigned)T;
        unsigned wq  = (unsigned)(T >> 32);
        int p = atomicAdd(&cnt[key >> 19], 1);
        pe[p] = (wq << 19) | (key & 0x7FFFFu);
    }
}

// ---- running-sum layer: hout[n] = bf16( E[n] + sum w * hsrc[src] ) ------
__global__ void slayer_kernel(const uint4* __restrict__ hsrc,
                              const uint4* __restrict__ E,
                              uint4* __restrict__ hout,
                              const unsigned* __restrict__ offs1,
                              const unsigned* __restrict__ pe) {
    int blk  = swz_block(blockIdx.x, gridDim.x);
    int gid  = blk * 256 + threadIdx.x;
    int wave = gid >> 6;
    int lane = gid & 63;
    int grp  = lane >> 3;
    int sub  = lane & 7;
    int n    = wave * 8 + grp;
    if (n >= N_NODES) return;
    unsigned ov = offs1[n];
    int beg = (n >> BSHIFT) * CAP + (int)(ov & 0xFFFFu);
    int end = beg + (int)(ov >> 16);
    float a0[8] = {0,0,0,0,0,0,0,0};
    float a1[8] = {0,0,0,0,0,0,0,0};
    int e = beg;
    for (; e + 2 <= end; e += 2) {
        unsigned p0 = pe[e], p1 = pe[e + 1];
        uint4 g0 = hsrc[(size_t)(p0 & 0x7FFFFu) * 8 + sub];
        uint4 g1 = hsrc[(size_t)(p1 & 0x7FFFFu) * 8 + sub];
        bf8_fma(g0, wdec(p0), a0);
        bf8_fma(g1, wdec(p1), a1);
    }
    if (e < end) {
        unsigned p0 = pe[e];
        uint4 g0 = hsrc[(size_t)(p0 & 0x7FFFFu) * 8 + sub];
        bf8_fma(g0, wdec(p0), a0);
    }
    size_t o8 = (size_t)n * 8 + sub;
    uint4 e0 = E[o8];
    a0[0] += a1[0] + blo(e0.x); a0[1] += a1[1] + bhi(e0.x);
    a0[2] += a1[2] + blo(e0.y); a0[3] += a1[3] + bhi(e0.y);
    a0[4] += a1[4] + blo(e0.z); a0[5] += a1[5] + bhi(e0.z);
    a0[6] += a1[6] + blo(e0.w); a0[7] += a1[7] + bhi(e0.w);
    uint4 r;
    r.x = bpack(a0[0], a0[1]); r.y = bpack(a0[2], a0[3]);
    r.z = bpack(a0[4], a0[5]); r.w = bpack(a0[6], a0[7]);
    hout[o8] = r;
}

// final: out = 0.25 * ( E[n] + sum w * S2[src] ), f32 nontemporal out
__global__ void final_kernel(const uint4* __restrict__ E,
                             const uint4* __restrict__ S2,
                             float* __restrict__ out,
                             const unsigned* __restrict__ offs1,
                             const unsigned* __restrict__ pe) {
    int blk  = swz_block(blockIdx.x, gridDim.x);
    int gid  = blk * 256 + threadIdx.x;
    int wave = gid >> 6;
    int lane = gid & 63;
    int grp  = lane >> 3;
    int sub  = lane & 7;
    int n    = wave * 8 + grp;
    if (n >= N_NODES) return;
    unsigned ov = offs1[n];
    int beg = (n >> BSHIFT) * CAP + (int)(ov & 0xFFFFu);
    int end = beg + (int)(ov >> 16);
    float a0[8] = {0,0,0,0,0,0,0,0};
    float a1[8] = {0,0,0,0,0,0,0,0};
    int e = beg;
    for (; e + 2 <= end; e += 2) {
        unsigned p0 = pe[e], p1 = pe[e + 1];
        uint4 g0 = S2[(size_t)(p0 & 0x7FFFFu) * 8 + sub];
        uint4 g1 = S2[(size_t)(p1 & 0x7FFFFu) * 8 + sub];
        bf8_fma(g0, wdec(p0), a0);
        bf8_fma(g1, wdec(p1), a1);
    }
    if (e < end) {
        unsigned p0 = pe[e];
        uint4 g0 = S2[(size_t)(p0 & 0x7FFFFu) * 8 + sub];
        bf8_fma(g0, wdec(p0), a0);
    }
    size_t o8 = (size_t)n * 8 + sub;
    uint4 e0 = E[o8];
    f32x4 ra, rb;
    ra.x = 0.25f * (blo(e0.x) + a0[0] + a1[0]);
    ra.y = 0.25f * (bhi(e0.x) + a0[1] + a1[1]);
    ra.z = 0.25f * (blo(e0.y) + a0[2] + a1[2]);
    ra.w = 0.25f * (bhi(e0.y) + a0[3] + a1[3]);
    rb.x = 0.25f * (blo(e0.z) + a0[4] + a1[4]);
    rb.y = 0.25f * (bhi(e0.z) + a0[5] + a1[5]);
    rb.z = 0.25f * (blo(e0.w) + a0[6] + a1[6]);
    rb.w = 0.25f * (bhi(e0.w) + a0[7] + a1[7]);
    f32x4* op = (f32x4*)out + (size_t)n * 16 + sub * 2;
    __builtin_nontemporal_store(ra, op);
    __builtin_nontemporal_store(rb, op + 1);
}

// ---------------- fallback (round-1 atomic) path ----------------
__global__ void init_fb_kernel(const float4* __restrict__ ue,
                               const float4* __restrict__ ie,
                               float4* __restrict__ h,
                               float4* __restrict__ hn,
                               float4* __restrict__ acc) {
    int i = blockIdx.x * blockDim.x + threadIdx.x;
    if (i >= NV4) return;
    const int ub = USER_NUM * EMBED_DIM / 4;
    float4 v = (i < ub) ? ue[i] : ie[i - ub];
    h[i] = v; acc[i] = v;
    hn[i] = make_float4(0.f, 0.f, 0.f, 0.f);
}

__global__ void spmm_fb_kernel(const float* __restrict__ h, float* __restrict__ hn,
                               const int* __restrict__ src, const int* __restrict__ dst,
                               const float* __restrict__ w) {
    int gid = blockIdx.x * blockDim.x + threadIdx.x;
    int wave = gid >> 6, lane = gid & 63;
    int nwave = (gridDim.x * blockDim.x) >> 6;
    for (int e = wave; e < N_EDGES; e += nwave) {
        float v = h[src[e] * 64 + lane] * w[e];
        atomicAdd(&hn[dst[e] * 64 + lane], v);
    }
}

template <int LAST>
__global__ void accum_fb_kernel(float4* __restrict__ acc, const float4* __restrict__ hn,
                                float4* __restrict__ zbuf) {
    int i = blockIdx.x * blockDim.x + threadIdx.x;
    if (i >= NV4) return;
    float4 a = acc[i], n = hn[i];
    a.x += n.x; a.y += n.y; a.z += n.z; a.w += n.w;
    if (LAST) { a.x *= 0.25f; a.y *= 0.25f; a.z *= 0.25f; a.w *= 0.25f; }
    acc[i] = a;
    if (!LAST) zbuf[i] = make_float4(0.f, 0.f, 0.f, 0.f);
}

extern "C" void kernel_launch(void* const* d_in, const int* in_sizes, int n_in,
                              void* d_out, int out_size, void* d_ws, size_t ws_size,
                              hipStream_t stream) {
    const float* ue  = (const float*)d_in[0];
    const float* ie  = (const float*)d_in[1];
    const float* w   = (const float*)d_in[2];
    const int*   src = (const int*)d_in[3];
    const int*   dst = (const int*)d_in[4];

    float* out = (float*)d_out;

    // workspace: E(64MB), S1(64MB), S2(64MB), tmp(u64 16MB padded),
    //            pe(uint 8MB padded), offs1(2MB), bcur(245)
    const size_t HB   = (size_t)N_NODES * 128;
    const size_t PADE = (size_t)NBUK * CAP;
    char*     base  = (char*)d_ws;
    uint4*    E     = (uint4*)base;
    uint4*    S1    = (uint4*)(base + HB);
    uint4*    S2    = (uint4*)(base + 2 * HB);
    u64*      tmp   = (u64*)(base + 3 * HB);
    unsigned* pe    = (unsigned*)(base + 3 * HB + PADE * 8);
    unsigned* offs1 = (unsigned*)(base + 3 * HB + PADE * 8 + PADE * 4);
    int*      bcur  = (int*)(base + 3 * HB + PADE * 12 + (size_t)N_NODES * 4);

    const size_t needed = 3 * HB + PADE * 12 + (size_t)N_NODES * 4
                        + (size_t)NBUK * 4;

    const int TB = 256;
    const int egrid = NV4 / TB;
    const int fgrid = (N_NODES / 8 * 64) / TB;        // 15625 (8 nodes/wave)

    if (ws_size >= needed) {
        (void)hipMemsetAsync(bcur, 0, (size_t)NBUK * 4, stream);
        pre_kernel<<<PGRID + CONVG, TB, 0, stream>>>(src, dst, w, bcur, tmp,
                                                     (const float4*)ue,
                                                     (const float4*)ie, E);
        fine_kernel<<<NBUK, TB, 0, stream>>>(tmp, bcur, offs1, pe);

        slayer_kernel<<<fgrid, TB, 0, stream>>>(E,  E, S1, offs1, pe);  // S1=E+A·E
        slayer_kernel<<<fgrid, TB, 0, stream>>>(S1, E, S2, offs1, pe);  // S2=E+A·S1
        final_kernel<<<fgrid, TB, 0, stream>>>(E, S2, out, offs1, pe);  // 0.25(E+A·S2)
    } else {
        // ---- fallback: atomic path ----
        float* A  = (float*)d_ws;
        float* Bf = A + NV;
        const int sgrid = 4096;
        init_fb_kernel<<<egrid, TB, 0, stream>>>((const float4*)ue, (const float4*)ie,
                                                 (float4*)A, (float4*)Bf, (float4*)out);
        spmm_fb_kernel<<<sgrid, TB, 0, stream>>>(A, Bf, src, dst, w);
        accum_fb_kernel<0><<<egrid, TB, 0, stream>>>((float4*)out, (const float4*)Bf, (float4*)A);
        spmm_fb_kernel<<<sgrid, TB, 0, stream>>>(Bf, A, src, dst, w);
        accum_fb_kernel<0><<<egrid, TB, 0, stream>>>((float4*)out, (const float4*)A, (float4*)Bf);
        spmm_fb_kernel<<<sgrid, TB, 0, stream>>>(A, Bf, src, dst, w);
        accum_fb_kernel<1><<<egrid, TB, 0, stream>>>((float4*)out, (const float4*)Bf, nullptr);
    }
}